// Round 10
// baseline (720.849 us; speedup 1.0000x reference)
//
#include <hip/hip_runtime.h>
#include <cstdint>
#include <cstddef>

#define NB 128
#define NT 512
#define NJ 21
#define NC 3
#define NH 64
#define JH 1344   // NJ*NH
#define G3 192    // 3*NH
#define OUT0 (NB*NJ*NC) // 8064
#define FB 4      // frames per k1 block (one per wave)

typedef __attribute__((ext_vector_type(8))) __bf16 bf16x8;
typedef __attribute__((ext_vector_type(4))) float f32x4;

__device__ __forceinline__ float bf2f(unsigned short u) {
  union { unsigned int i; float f; } v; v.i = ((unsigned int)u) << 16; return v.f;
}
__device__ __forceinline__ unsigned short f2bf(float f) {
  union { float f; unsigned int i; } v; v.f = f;
  unsigned int x = v.i;
  unsigned int lsb = (x >> 16) & 1u;
  x += 0x7fffu + lsb;
  return (unsigned short)(x >> 16);
}
__device__ __forceinline__ unsigned int pk_bf16(float lo, float hi) {
  unsigned int r;
  asm("v_cvt_pk_bf16_f32 %0, %1, %2" : "=v"(r) : "v"(lo), "v"(hi));
  return r;
}
__device__ __forceinline__ unsigned int scale2(unsigned int u, float s) {
  float lo = __uint_as_float(u << 16);
  float hi = __uint_as_float(u & 0xffff0000u);
  return pk_bf16(lo * s, hi * s);
}

// ---------------- K0: convert W_ih (192x1344 f32) to bf16
__global__ __launch_bounds__(256) void k0_convw(
    const float* __restrict__ W, unsigned short* __restrict__ Wbf) {
  const int ti = blockIdx.x*256 + threadIdx.x;
  const float4 v = ((const float4*)W)[ti];
  uint2 o;
  o.x = (unsigned int)f2bf(v.x) | ((unsigned int)f2bf(v.y) << 16);
  o.y = (unsigned int)f2bf(v.z) | ((unsigned int)f2bf(v.w) << 16);
  ((uint2*)Wbf)[ti] = o;
}

// ---------------- K1: fused GCN x2 via MFMA (unchanged, passing)
__global__ __launch_bounds__(256, 2) void k1_fused(
    const float* __restrict__ x, const float* __restrict__ A,
    const float* __restrict__ W1, const float* __restrict__ b1,
    const float* __restrict__ W2, const float* __restrict__ b2,
    const float* __restrict__ Wa,
    unsigned short* __restrict__ h2out, float* __restrict__ scorepart) {
  __shared__ unsigned short h1s[FB*32*72];
  __shared__ unsigned short us[FB*64*40];
  __shared__ unsigned short w2s[64*72];
  __shared__ unsigned short adjs[32*40];
  __shared__ unsigned short h2st[FB*NJ*72];
  __shared__ float afs[NJ*NJ];
  __shared__ float xs[4][64];
  __shared__ float ags[4][64];
  __shared__ float spred[4][NJ];

  const int tid = threadIdx.x;
  const int w = tid >> 6, l = tid & 63;
  const int q = l >> 4, r = l & 15;
  const int b = blockIdx.x >> 7, ch = blockIdx.x & 127;
  const int t0 = ch * FB;

  for (int i = tid; i < NJ*NJ; i += 256) afs[i] = A[i];
  for (int i = tid; i < 1024; i += 256) {
    const int ii = i >> 5, jj = i & 31;
    adjs[ii*40 + jj] = (ii < NJ && jj < NJ) ? f2bf(A[ii*NJ + jj]) : (unsigned short)0;
  }
  {
    const int h = tid & 63, qd = tid >> 6;
    const int g0 = qd * 16;
#pragma unroll
    for (int e = 0; e < 16; e += 2) {
      const float v0 = W2[h*64 + g0 + e], v1 = W2[h*64 + g0 + e + 1];
      ((unsigned int*)w2s)[h*36 + ((g0 + e) >> 1)] = pk_bf16(v0, v1);
    }
  }
#pragma unroll
  for (int j = NJ; j < 32; ++j)
    ((unsigned int*)h1s)[(w*32 + j)*36 + (l & 31)] = 0u;

  const float w1r0 = W1[l*3+0], w1r1 = W1[l*3+1], w1r2 = W1[l*3+2];
  const float b1h = b1[l];
  float b2v[4][4], wav[4][4];
#pragma unroll
  for (int mt = 0; mt < 4; ++mt)
#pragma unroll
    for (int rg = 0; rg < 4; ++rg) {
      const int h = mt*16 + q*4 + rg;
      b2v[mt][rg] = b2[h]; wav[mt][rg] = Wa[h];
    }
  __syncthreads();   // B0

  {
    const size_t fr = (size_t)(b*NT + t0 + w);
    if (l < NJ*NC) xs[w][l] = x[fr*(NJ*NC) + l];
    if (l < NJ*NC) {
      const int ji = l / 3, c = l - ji*3;
      float s = 0.f;
#pragma unroll
      for (int j = 0; j < NJ; ++j) s += afs[ji*NJ + j] * xs[w][j*3 + c];
      ags[w][l] = s;
    }
#pragma unroll
    for (int j = 0; j < NJ; ++j) {
      float v = b1h + w1r0*ags[w][j*3+0] + w1r1*ags[w][j*3+1] + w1r2*ags[w][j*3+2];
      v = fmaxf(v, 0.f);
      h1s[(w*32 + j)*72 + l] = f2bf(v);
    }
  }
  __syncthreads();   // B1

  bf16x8 bw[2][4];
#pragma unroll
  for (int ks = 0; ks < 2; ++ks)
#pragma unroll
    for (int nt = 0; nt < 4; ++nt)
      bw[ks][nt] = *(const bf16x8*)(&w2s[(nt*16 + r)*72 + (ks*4 + q)*8]);
  f32x4 acc1[2][4];
#pragma unroll
  for (int i = 0; i < 2; ++i)
#pragma unroll
    for (int j2 = 0; j2 < 4; ++j2) acc1[i][j2] = (f32x4)0.f;
#pragma unroll
  for (int mti = 0; mti < 2; ++mti) {
    const int row = (w*2 + mti)*16 + r;
#pragma unroll
    for (int ks = 0; ks < 2; ++ks) {
      const bf16x8 af = *(const bf16x8*)(&h1s[row*72 + (ks*4 + q)*8]);
#pragma unroll
      for (int nt = 0; nt < 4; ++nt)
        acc1[mti][nt] = __builtin_amdgcn_mfma_f32_16x16x32_bf16(af, bw[ks][nt], acc1[mti][nt], 0,0,0);
    }
  }
#pragma unroll
  for (int mti = 0; mti < 2; ++mti)
#pragma unroll
    for (int nt = 0; nt < 4; ++nt) {
      const int h = nt*16 + r;
#pragma unroll
      for (int rp = 0; rp < 2; ++rp) {
        const int jp = mti*16 + q*4 + rp*2;
        ((unsigned int*)us)[(w*64 + h)*20 + (jp >> 1)] =
            pk_bf16(acc1[mti][nt][rp*2], acc1[mti][nt][rp*2+1]);
      }
    }
  __syncthreads();   // B2

  bf16x8 badj[2];
#pragma unroll
  for (int nt = 0; nt < 2; ++nt)
    badj[nt] = *(const bf16x8*)(&adjs[(nt*16 + r)*40 + q*8]);
  f32x4 acc2[4][2];
#pragma unroll
  for (int i = 0; i < 4; ++i) { acc2[i][0] = (f32x4)0.f; acc2[i][1] = (f32x4)0.f; }
#pragma unroll
  for (int mt = 0; mt < 4; ++mt) {
    const int h = mt*16 + r;
    const bf16x8 af = *(const bf16x8*)(&us[(w*64 + h)*40 + q*8]);
#pragma unroll
    for (int nt = 0; nt < 2; ++nt)
      acc2[mt][nt] = __builtin_amdgcn_mfma_f32_16x16x32_bf16(af, badj[nt], acc2[mt][nt], 0,0,0);
  }
  float sp0 = 0.f, sp1 = 0.f;
#pragma unroll
  for (int nt = 0; nt < 2; ++nt) {
    const int i = nt*16 + r;
    if (i < NJ) {
#pragma unroll
      for (int mt = 0; mt < 4; ++mt)
#pragma unroll
        for (int rp = 0; rp < 2; ++rp) {
          const int h0 = mt*16 + q*4 + rp*2;
          const float v0 = fmaxf(acc2[mt][nt][rp*2]   + b2v[mt][rp*2],   0.f);
          const float v1 = fmaxf(acc2[mt][nt][rp*2+1] + b2v[mt][rp*2+1], 0.f);
          if (nt == 0) sp0 += v0*wav[mt][rp*2] + v1*wav[mt][rp*2+1];
          else         sp1 += v0*wav[mt][rp*2] + v1*wav[mt][rp*2+1];
          ((unsigned int*)h2st)[(w*NJ + i)*36 + (h0 >> 1)] = pk_bf16(v0, v1);
        }
    }
  }
  sp0 += __shfl_xor(sp0, 16); sp0 += __shfl_xor(sp0, 32);
  sp1 += __shfl_xor(sp1, 16); sp1 += __shfl_xor(sp1, 32);
  if (l < 16) spred[w][l] = sp0;
  if (l < 5)  spred[w][16 + l] = sp1;
  __syncthreads();   // B3

  if (tid < NJ)
    scorepart[((size_t)b*128 + ch)*NJ + tid] =
      spred[0][tid] + spred[1][tid] + spred[2][tid] + spred[3][tid];

  const size_t gbase = (size_t)(b*NT + t0) * JH;
  for (int cid = tid; cid < FB*NJ*8; cid += 256) {
    const int f = cid / (NJ*8), rem = cid - f*(NJ*8);
    const int i = rem >> 3, p = rem & 7;
    const uint4 v = *(const uint4*)(&h2st[(f*NJ + i)*72 + p*8]);
    *(uint4*)(&h2out[gbase + (size_t)f*JH + i*64 + p*8]) = v;
  }
}

// ---------------- K2: reduce score partials, softmax over joints
__global__ __launch_bounds__(64) void k2_attn(
    const float* __restrict__ scorepart, float* __restrict__ attn,
    float* __restrict__ out_attn) {
  __shared__ float ss[NJ];
  const int b = blockIdx.x, tid = threadIdx.x;
  if (tid < NJ) {
    float s = 0.f;
    for (int ch = 0; ch < 128; ++ch) s += scorepart[(b*128 + ch)*NJ + tid];
    ss[tid] = s * (1.0f/NT);
  }
  __syncthreads();
  float m = -1e30f;
  for (int j = 0; j < NJ; ++j) m = fmaxf(m, ss[j]);
  float sum = 0.f;
  for (int j = 0; j < NJ; ++j) sum += expf(ss[j] - m);
  if (tid < NJ) {
    float a = expf(ss[tid] - m) / sum;
    attn[b*NJ + tid] = a;
    out_attn[b*NJ + tid] = a;
  }
}

// ---------------- K34: fused xproj-producer + GRU-consumer (overlap).
// Blocks 0..7: k4-role (GRU, 16 batches each, structure = proven R9 kernel +
// per-chunk acquire-spin). Blocks 8..263: k3-role (b = (blk-8)>>1, half), 4
// sequential PHASES in chunk order c=0..3, phase = rows [c*128+half*64, +64),
// 2 subs x 32 rows. All 256 producers hit chunk 0 first -> chunk c ready at
// ~(c+1)/4 of producer time; consumer needs chunk c at ~start + c*73us.
// Sync: producer __threadfence + release atomicAdd; consumer acquire spin.
// cnt[g*4+c] target = 32 (16 b x 2 halves).
struct SK3 {
  unsigned short Ab[2][2][32*32];   // [sub][dbuf]  8 KB
  unsigned short Bb[2][192*32];     // [dbuf] shared by subs, 24 KB
};
struct SK4 { uint4 hb4[2][2][4][16]; };  // 4 KB
union SMem34 { SK3 k3; SK4 k4; };

__global__ __launch_bounds__(512, 4) void k34_fused(
    const unsigned short* __restrict__ h2, const unsigned short* __restrict__ Wbf,
    const float* __restrict__ b_ih, const float* __restrict__ b_hh,
    const float* __restrict__ attn, float* __restrict__ xproj,
    const float* __restrict__ W_hh, float* __restrict__ hT,
    int* __restrict__ cnt) {
  __shared__ SMem34 sm;
  const int tid = threadIdx.x;

  if (blockIdx.x < 8) {
    // ---------------- k4 role: MFMA GRU (R9 structure)
    const int g = blockIdx.x;
    const int w = tid >> 6, l = tid & 63, q = l >> 4, r15 = l & 15;
    const int b0 = g * 16;

    for (int i = tid; i < 256; i += 512)
      ((uint4*)sm.k4.hb4)[i] = uint4{0u,0u,0u,0u};

    bf16x8 afr[2][2];
    int chv[2]; float bn_[2];
#pragma unroll
    for (int i = 0; i < 2; ++i) {
      const int mt = 2*w + i;
      const int gate = r15 & 3;
      const int cha = 8*(mt >> 1) + 2*(r15 >> 2) + (mt & 1);
#pragma unroll
      for (int ks = 0; ks < 2; ++ks) {
        union { bf16x8 v; unsigned int u[4]; } tu;
        if (gate < 3) {
          const float* src = W_hh + (size_t)(gate*NH + cha)*NH + ks*32 + q*8;
          const float4 a = *(const float4*)(src);
          const float4 b = *(const float4*)(src + 4);
          tu.u[0] = pk_bf16(a.x, a.y); tu.u[1] = pk_bf16(a.z, a.w);
          tu.u[2] = pk_bf16(b.x, b.y); tu.u[3] = pk_bf16(b.z, b.w);
        } else {
          tu.u[0]=0u; tu.u[1]=0u; tu.u[2]=0u; tu.u[3]=0u;
        }
        afr[i][ks] = tu.v;
      }
      chv[i] = 8*w + 2*q + i;
      bn_[i] = b_hh[2*NH + chv[i]];
    }
    const int half = w >> 2, qblk = w & 3;

    const float* xrow[2][3];
#pragma unroll
    for (int i = 0; i < 2; ++i)
#pragma unroll
      for (int e = 0; e < 3; ++e)
        xrow[i][e] = xproj + (size_t)((b0 + r15)*G3 + e*NH + chv[i]) * NT;

    // wait for chunk 0 (also publishes hb4 zero-init via syncthreads)
    if (tid == 0) {
      while (__hip_atomic_load(&cnt[g*4 + 0], __ATOMIC_ACQUIRE,
                               __HIP_MEMORY_SCOPE_AGENT) < 32)
        __builtin_amdgcn_s_sleep(2);
    }
    __syncthreads();

    float hprev[2] = {0.f, 0.f};
    f32x4 cur[2][3], nxt[2][3];
#pragma unroll
    for (int i = 0; i < 2; ++i)
#pragma unroll
      for (int e = 0; e < 3; ++e) { cur[i][e] = *(const f32x4*)(xrow[i][e]); nxt[i][e] = cur[i][e]; }

    for (int tg = 0; tg < NT; tg += 4) {
      if (tg + 4 < NT && ((tg + 4) & 127) == 0) {
        const int c = (tg + 4) >> 7;
        if (tid == 0) {
          while (__hip_atomic_load(&cnt[g*4 + c], __ATOMIC_ACQUIRE,
                                   __HIP_MEMORY_SCOPE_AGENT) < 32)
            __builtin_amdgcn_s_sleep(2);
        }
        __syncthreads();
      }
      if (tg + 4 < NT) {
#pragma unroll
        for (int i = 0; i < 2; ++i)
#pragma unroll
          for (int e = 0; e < 3; ++e) nxt[i][e] = *(const f32x4*)(xrow[i][e] + tg + 4);
      }
#pragma unroll
      for (int p = 0; p < 4; ++p) {
        const int rb = p & 1, wb = rb ^ 1;
        const bf16x8 bh0 = *(const bf16x8*)(&sm.k4.hb4[rb][0][q][r15]);
        const bf16x8 bh1 = *(const bf16x8*)(&sm.k4.hb4[rb][1][q][r15]);
        f32x4 acc[2];
        acc[0] = (f32x4)0.f; acc[1] = (f32x4)0.f;
        acc[0] = __builtin_amdgcn_mfma_f32_16x16x32_bf16(afr[0][0], bh0, acc[0], 0,0,0);
        acc[1] = __builtin_amdgcn_mfma_f32_16x16x32_bf16(afr[1][0], bh0, acc[1], 0,0,0);
        acc[0] = __builtin_amdgcn_mfma_f32_16x16x32_bf16(afr[0][1], bh1, acc[0], 0,0,0);
        acc[1] = __builtin_amdgcn_mfma_f32_16x16x32_bf16(afr[1][1], bh1, acc[1], 0,0,0);
        float hnew[2];
#pragma unroll
        for (int i = 0; i < 2; ++i) {
          const float xr = cur[i][0][p], xz = cur[i][1][p], xn = cur[i][2][p];
          const float hn = acc[i][2] + bn_[i];
          const float rr = __builtin_amdgcn_rcpf(1.f + __expf(-(xr + acc[i][0])));
          const float zz = __builtin_amdgcn_rcpf(1.f + __expf(-(xz + acc[i][1])));
          const float nx = xn + rr*hn;
          const float nn = 2.f*__builtin_amdgcn_rcpf(1.f + __expf(-2.f*nx)) - 1.f;
          hnew[i] = nn + zz*(hprev[i] - nn);
          hprev[i] = hnew[i];
        }
        ((unsigned int*)&sm.k4.hb4[wb][half][qblk][r15])[q] = pk_bf16(hnew[0], hnew[1]);
        asm volatile("s_waitcnt lgkmcnt(0)" ::: "memory");
        __builtin_amdgcn_s_barrier();
        __builtin_amdgcn_sched_barrier(0);   // pin next reads after barrier
      }
#pragma unroll
      for (int i = 0; i < 2; ++i)
#pragma unroll
        for (int e = 0; e < 3; ++e) cur[i][e] = nxt[i][e];
    }

#pragma unroll
    for (int i = 0; i < 2; ++i)
      hT[(size_t)(b0 + r15)*NH + chv[i]] = hprev[i];
    return;
  }

  // ---------------- k3 role: xproj = (h2*attn) @ W_ih^T + bias, [b][g][t]
  const int kb = blockIdx.x - 8;
  const int b = kb >> 1, hf = kb & 1;
  const int sub = tid >> 8, stid = tid & 255;
  const int w = (tid >> 6) & 3, l = tid & 63;
  const int lq = l >> 4, lr = l & 15;
  const int wm = w >> 1, wn = w & 1;

  // A staging (per sub, rows 0..31 of the phase tile): threads stid<128
  const unsigned short* gA0 = nullptr; int ldsA = 0;
  if (stid < 128) {
    const int rr = stid >> 2, j = stid & 3;
    gA0 = h2 + (size_t)(b*NT + rr)*JH + j*8;   // + R0*JH per phase
    ldsA = rr*32 + ((j ^ ((rr >> 1) & 3)) << 3);
  }
  // B staging: lc = tid (g 0..127) and, for tid<256, lc = 512+tid (g 128..191)
  const unsigned short* gB0; int ldsB0;
  { const int g = tid >> 2, j = tid & 3;
    gB0 = Wbf + (size_t)g*JH + j*8;
    ldsB0 = g*32 + ((j ^ ((g >> 1) & 3)) << 3); }
  const unsigned short* gB1 = nullptr; int ldsB1 = 0;
  if (tid < 256) {
    const int lc = 512 + tid, g = lc >> 2, j = lc & 3;
    gB1 = Wbf + (size_t)g*JH + j*8;
    ldsB1 = g*32 + ((j ^ ((g >> 1) & 3)) << 3);
  }
  // fragment offsets
  int aoff, boff[6];
  { const int row = wm*16 + lr;
    aoff = row*32 + ((lq ^ ((row >> 1) & 3)) << 3); }
#pragma unroll
  for (int nt = 0; nt < 6; ++nt) {
    const int g = wn*96 + nt*16 + lr;
    boff[nt] = g*32 + ((lq ^ ((g >> 1) & 3)) << 3);
  }
  float bias[6];
#pragma unroll
  for (int nt = 0; nt < 6; ++nt) {
    const int g = wn*96 + nt*16 + lr;
    bias[nt] = b_ih[g] + (g < 2*NH ? b_hh[g] : 0.f);
  }

  for (int c = 0; c < 4; ++c) {
    const int R0 = c*128 + hf*64 + sub*32;
    const unsigned short* gAp = gA0 + (size_t)R0*JH;

    f32x4 acc[6];
#pragma unroll
    for (int nt = 0; nt < 6; ++nt) acc[nt] = (f32x4)0.f;

    // prologue ks=0
    {
      const float s = attn[b*NJ + 0];
      if (stid < 128) *(uint4*)(&sm.k3.Ab[sub][0][ldsA]) = *(const uint4*)(gAp);
      uint4 v = *(const uint4*)(gB0);
      v.x = scale2(v.x, s); v.y = scale2(v.y, s);
      v.z = scale2(v.z, s); v.w = scale2(v.w, s);
      *(uint4*)(&sm.k3.Bb[0][ldsB0]) = v;
      if (tid < 256) {
        uint4 u = *(const uint4*)(gB1);
        u.x = scale2(u.x, s); u.y = scale2(u.y, s);
        u.z = scale2(u.z, s); u.w = scale2(u.w, s);
        *(uint4*)(&sm.k3.Bb[0][ldsB1]) = u;
      }
    }
    __syncthreads();

    for (int ks = 0; ks < 42; ++ks) {
      const int curb = ks & 1;
      uint4 av, bv0, bv1;
      if (ks < 41) {
        const int kk = (ks+1)*32;
        if (stid < 128) av = *(const uint4*)(gAp + kk);
        bv0 = *(const uint4*)(gB0 + kk);
        if (tid < 256) bv1 = *(const uint4*)(gB1 + kk);
      }
      const bf16x8 af = *(const bf16x8*)(&sm.k3.Ab[sub][curb][aoff]);
      bf16x8 bfr[6];
#pragma unroll
      for (int nt = 0; nt < 6; ++nt) bfr[nt] = *(const bf16x8*)(&sm.k3.Bb[curb][boff[nt]]);
#pragma unroll
      for (int nt = 0; nt < 6; ++nt)
        acc[nt] = __builtin_amdgcn_mfma_f32_16x16x32_bf16(af, bfr[nt], acc[nt], 0, 0, 0);
      if (ks < 41) {
        const float s = attn[b*NJ + ((ks+1) >> 1)];
        if (stid < 128) *(uint4*)(&sm.k3.Ab[sub][curb^1][ldsA]) = av;
        bv0.x = scale2(bv0.x, s); bv0.y = scale2(bv0.y, s);
        bv0.z = scale2(bv0.z, s); bv0.w = scale2(bv0.w, s);
        *(uint4*)(&sm.k3.Bb[curb^1][ldsB0]) = bv0;
        if (tid < 256) {
          bv1.x = scale2(bv1.x, s); bv1.y = scale2(bv1.y, s);
          bv1.z = scale2(bv1.z, s); bv1.w = scale2(bv1.w, s);
          *(uint4*)(&sm.k3.Bb[curb^1][ldsB1]) = bv1;
        }
      }
      __syncthreads();
    }

    // epilogue: store float4 along t
#pragma unroll
    for (int nt = 0; nt < 6; ++nt) {
      const int g = wn*96 + nt*16 + lr;
      const int trow = R0 + wm*16 + lq*4;
      float4 o;
      o.x = acc[nt][0] + bias[nt];
      o.y = acc[nt][1] + bias[nt];
      o.z = acc[nt][2] + bias[nt];
      o.w = acc[nt][3] + bias[nt];
      *(float4*)(&xproj[(size_t)(b*G3 + g)*NT + trow]) = o;
    }
    __threadfence();
    __syncthreads();
    if (tid == 0)
      __hip_atomic_fetch_add(&cnt[(b >> 4)*4 + c], 1, __ATOMIC_RELEASE,
                             __HIP_MEMORY_SCOPE_AGENT);
  }
}

// ---------------- K5: head
__global__ __launch_bounds__(256) void k5_head(
    const float* __restrict__ hT, const float* __restrict__ W_head,
    const float* __restrict__ b_head, float* __restrict__ out) {
  const int idx = blockIdx.x*256 + threadIdx.x;
  if (idx >= NB*63) return;
  const int b = idx / 63, rr = idx % 63;
  const float* hv = hT + b*NH;
  const float* wr = W_head + rr*NH;
  float acc = b_head[rr];
#pragma unroll
  for (int k = 0; k < NH; ++k) acc += hv[k]*wr[k];
  out[idx] = acc;
}

extern "C" void kernel_launch(void* const* d_in, const int* in_sizes, int n_in,
                              void* d_out, int out_size, void* d_ws, size_t ws_size,
                              hipStream_t stream) {
  const float* x      = (const float*)d_in[0];
  const float* A      = (const float*)d_in[1];
  const float* W1     = (const float*)d_in[2];
  const float* b1     = (const float*)d_in[3];
  const float* W2     = (const float*)d_in[4];
  const float* b2     = (const float*)d_in[5];
  const float* Wa     = (const float*)d_in[6];
  // d_in[7] = ba : softmax-invariant, unused
  const float* W_ih   = (const float*)d_in[8];
  const float* b_ih   = (const float*)d_in[9];
  const float* W_hh   = (const float*)d_in[10];
  const float* b_hh   = (const float*)d_in[11];
  const float* W_head = (const float*)d_in[12];
  const float* b_head = (const float*)d_in[13];
  float* out = (float*)d_out;

  char* ws = (char*)d_ws;
  size_t off = 0;
  unsigned short* h2 = (unsigned short*)(ws + off); off += (size_t)NB*NT*JH*2;   // 176 MB
  float* scorepart   = (float*)(ws + off);          off += (size_t)NB*128*NJ*4;  // 1.38 MB
  float* attn        = (float*)(ws + off);          off += (size_t)NB*NJ*4;
  off = (off + 15) & ~(size_t)15;
  float* xproj       = (float*)(ws + off);          off += (size_t)NB*NT*G3*4;   // 50 MB, [b][g][t]
  float* hT          = (float*)(ws + off);          off += (size_t)NB*NH*4;
  off = (off + 15) & ~(size_t)15;
  unsigned short* Wbf = (unsigned short*)(ws + off); off += (size_t)G3*JH*2;     // 516 KB
  off = (off + 15) & ~(size_t)15;
  int* cnt           = (int*)(ws + off);            off += 32*sizeof(int);

  hipMemsetAsync(cnt, 0, 32*sizeof(int), stream);
  k0_convw<<<dim3(252),       256, 0, stream>>>(W_ih, Wbf);
  k1_fused<<<dim3(NB*128),    256, 0, stream>>>(x, A, W1, b1, W2, b2, Wa, h2, scorepart);
  k2_attn<<<dim3(NB),          64, 0, stream>>>(scorepart, attn, out + OUT0);
  k34_fused<<<dim3(264),      512, 0, stream>>>(h2, Wbf, b_ih, b_hh, attn, xproj, W_hh, hT, cnt);
  k5_head<<<dim3((NB*63 + 255)/256), 256, 0, stream>>>(hT, W_head, b_head, out);
}

// Round 11
// 500.720 us; speedup vs baseline: 1.4396x; 1.4396x over previous
//
#include <hip/hip_runtime.h>
#include <cstdint>
#include <cstddef>

#define NB 128
#define NT 512
#define NJ 21
#define NC 3
#define NH 64
#define JH 1344   // NJ*NH
#define G3 192    // 3*NH
#define OUT0 (NB*NJ*NC) // 8064
#define FB 4      // frames per k1 block (one per wave)

typedef __attribute__((ext_vector_type(8))) __bf16 bf16x8;
typedef __attribute__((ext_vector_type(4))) float f32x4;

__device__ __forceinline__ float bf2f(unsigned short u) {
  union { unsigned int i; float f; } v; v.i = ((unsigned int)u) << 16; return v.f;
}
__device__ __forceinline__ unsigned short f2bf(float f) {
  union { float f; unsigned int i; } v; v.f = f;
  unsigned int x = v.i;
  unsigned int lsb = (x >> 16) & 1u;
  x += 0x7fffu + lsb;
  return (unsigned short)(x >> 16);
}
__device__ __forceinline__ unsigned int pk_bf16(float lo, float hi) {
  unsigned int r;
  asm("v_cvt_pk_bf16_f32 %0, %1, %2" : "=v"(r) : "v"(lo), "v"(hi));
  return r;
}
__device__ __forceinline__ unsigned int scale2(unsigned int u, float s) {
  float lo = __uint_as_float(u << 16);
  float hi = __uint_as_float(u & 0xffff0000u);
  return pk_bf16(lo * s, hi * s);
}

// ---------------- K0: convert W_ih (192x1344 f32) to bf16
__global__ __launch_bounds__(256) void k0_convw(
    const float* __restrict__ W, unsigned short* __restrict__ Wbf) {
  const int ti = blockIdx.x*256 + threadIdx.x;
  const float4 v = ((const float4*)W)[ti];
  uint2 o;
  o.x = (unsigned int)f2bf(v.x) | ((unsigned int)f2bf(v.y) << 16);
  o.y = (unsigned int)f2bf(v.z) | ((unsigned int)f2bf(v.w) << 16);
  ((uint2*)Wbf)[ti] = o;
}

// ---------------- K1: fused GCN x2 via MFMA, linear padded LDS
__global__ __launch_bounds__(256, 2) void k1_fused(
    const float* __restrict__ x, const float* __restrict__ A,
    const float* __restrict__ W1, const float* __restrict__ b1,
    const float* __restrict__ W2, const float* __restrict__ b2,
    const float* __restrict__ Wa,
    unsigned short* __restrict__ h2out, float* __restrict__ scorepart) {
  __shared__ unsigned short h1s[FB*32*72];
  __shared__ unsigned short us[FB*64*40];
  __shared__ unsigned short w2s[64*72];
  __shared__ unsigned short adjs[32*40];
  __shared__ unsigned short h2st[FB*NJ*72];
  __shared__ float afs[NJ*NJ];
  __shared__ float xs[4][64];
  __shared__ float ags[4][64];
  __shared__ float spred[4][NJ];

  const int tid = threadIdx.x;
  const int w = tid >> 6, l = tid & 63;
  const int q = l >> 4, r = l & 15;
  const int b = blockIdx.x >> 7, ch = blockIdx.x & 127;
  const int t0 = ch * FB;

  for (int i = tid; i < NJ*NJ; i += 256) afs[i] = A[i];
  for (int i = tid; i < 1024; i += 256) {
    const int ii = i >> 5, jj = i & 31;
    adjs[ii*40 + jj] = (ii < NJ && jj < NJ) ? f2bf(A[ii*NJ + jj]) : (unsigned short)0;
  }
  {
    const int h = tid & 63, qd = tid >> 6;
    const int g0 = qd * 16;
#pragma unroll
    for (int e = 0; e < 16; e += 2) {
      const float v0 = W2[h*64 + g0 + e], v1 = W2[h*64 + g0 + e + 1];
      ((unsigned int*)w2s)[h*36 + ((g0 + e) >> 1)] = pk_bf16(v0, v1);
    }
  }
#pragma unroll
  for (int j = NJ; j < 32; ++j)
    ((unsigned int*)h1s)[(w*32 + j)*36 + (l & 31)] = 0u;

  const float w1r0 = W1[l*3+0], w1r1 = W1[l*3+1], w1r2 = W1[l*3+2];
  const float b1h = b1[l];
  float b2v[4][4], wav[4][4];
#pragma unroll
  for (int mt = 0; mt < 4; ++mt)
#pragma unroll
    for (int rg = 0; rg < 4; ++rg) {
      const int h = mt*16 + q*4 + rg;
      b2v[mt][rg] = b2[h]; wav[mt][rg] = Wa[h];
    }
  __syncthreads();   // B0

  {
    const size_t fr = (size_t)(b*NT + t0 + w);
    if (l < NJ*NC) xs[w][l] = x[fr*(NJ*NC) + l];
    if (l < NJ*NC) {
      const int ji = l / 3, c = l - ji*3;
      float s = 0.f;
#pragma unroll
      for (int j = 0; j < NJ; ++j) s += afs[ji*NJ + j] * xs[w][j*3 + c];
      ags[w][l] = s;
    }
#pragma unroll
    for (int j = 0; j < NJ; ++j) {
      float v = b1h + w1r0*ags[w][j*3+0] + w1r1*ags[w][j*3+1] + w1r2*ags[w][j*3+2];
      v = fmaxf(v, 0.f);
      h1s[(w*32 + j)*72 + l] = f2bf(v);
    }
  }
  __syncthreads();   // B1

  bf16x8 bw[2][4];
#pragma unroll
  for (int ks = 0; ks < 2; ++ks)
#pragma unroll
    for (int nt = 0; nt < 4; ++nt)
      bw[ks][nt] = *(const bf16x8*)(&w2s[(nt*16 + r)*72 + (ks*4 + q)*8]);
  f32x4 acc1[2][4];
#pragma unroll
  for (int i = 0; i < 2; ++i)
#pragma unroll
    for (int j2 = 0; j2 < 4; ++j2) acc1[i][j2] = (f32x4)0.f;
#pragma unroll
  for (int mti = 0; mti < 2; ++mti) {
    const int row = (w*2 + mti)*16 + r;
#pragma unroll
    for (int ks = 0; ks < 2; ++ks) {
      const bf16x8 af = *(const bf16x8*)(&h1s[row*72 + (ks*4 + q)*8]);
#pragma unroll
      for (int nt = 0; nt < 4; ++nt)
        acc1[mti][nt] = __builtin_amdgcn_mfma_f32_16x16x32_bf16(af, bw[ks][nt], acc1[mti][nt], 0,0,0);
    }
  }
#pragma unroll
  for (int mti = 0; mti < 2; ++mti)
#pragma unroll
    for (int nt = 0; nt < 4; ++nt) {
      const int h = nt*16 + r;
#pragma unroll
      for (int rp = 0; rp < 2; ++rp) {
        const int jp = mti*16 + q*4 + rp*2;
        ((unsigned int*)us)[(w*64 + h)*20 + (jp >> 1)] =
            pk_bf16(acc1[mti][nt][rp*2], acc1[mti][nt][rp*2+1]);
      }
    }
  __syncthreads();   // B2

  bf16x8 badj[2];
#pragma unroll
  for (int nt = 0; nt < 2; ++nt)
    badj[nt] = *(const bf16x8*)(&adjs[(nt*16 + r)*40 + q*8]);
  f32x4 acc2[4][2];
#pragma unroll
  for (int i = 0; i < 4; ++i) { acc2[i][0] = (f32x4)0.f; acc2[i][1] = (f32x4)0.f; }
#pragma unroll
  for (int mt = 0; mt < 4; ++mt) {
    const int h = mt*16 + r;
    const bf16x8 af = *(const bf16x8*)(&us[(w*64 + h)*40 + q*8]);
#pragma unroll
    for (int nt = 0; nt < 2; ++nt)
      acc2[mt][nt] = __builtin_amdgcn_mfma_f32_16x16x32_bf16(af, badj[nt], acc2[mt][nt], 0,0,0);
  }
  float sp0 = 0.f, sp1 = 0.f;
#pragma unroll
  for (int nt = 0; nt < 2; ++nt) {
    const int i = nt*16 + r;
    if (i < NJ) {
#pragma unroll
      for (int mt = 0; mt < 4; ++mt)
#pragma unroll
        for (int rp = 0; rp < 2; ++rp) {
          const int h0 = mt*16 + q*4 + rp*2;
          const float v0 = fmaxf(acc2[mt][nt][rp*2]   + b2v[mt][rp*2],   0.f);
          const float v1 = fmaxf(acc2[mt][nt][rp*2+1] + b2v[mt][rp*2+1], 0.f);
          if (nt == 0) sp0 += v0*wav[mt][rp*2] + v1*wav[mt][rp*2+1];
          else         sp1 += v0*wav[mt][rp*2] + v1*wav[mt][rp*2+1];
          ((unsigned int*)h2st)[(w*NJ + i)*36 + (h0 >> 1)] = pk_bf16(v0, v1);
        }
    }
  }
  sp0 += __shfl_xor(sp0, 16); sp0 += __shfl_xor(sp0, 32);
  sp1 += __shfl_xor(sp1, 16); sp1 += __shfl_xor(sp1, 32);
  if (l < 16) spred[w][l] = sp0;
  if (l < 5)  spred[w][16 + l] = sp1;
  __syncthreads();   // B3

  if (tid < NJ)
    scorepart[((size_t)b*128 + ch)*NJ + tid] =
      spred[0][tid] + spred[1][tid] + spred[2][tid] + spred[3][tid];

  const size_t gbase = (size_t)(b*NT + t0) * JH;
  for (int cid = tid; cid < FB*NJ*8; cid += 256) {
    const int f = cid / (NJ*8), rem = cid - f*(NJ*8);
    const int i = rem >> 3, p = rem & 7;
    const uint4 v = *(const uint4*)(&h2st[(f*NJ + i)*72 + p*8]);
    *(uint4*)(&h2out[gbase + (size_t)f*JH + i*64 + p*8]) = v;
  }
}

// ---------------- K2: reduce score partials, softmax over joints
__global__ __launch_bounds__(64) void k2_attn(
    const float* __restrict__ scorepart, float* __restrict__ attn,
    float* __restrict__ out_attn) {
  __shared__ float ss[NJ];
  const int b = blockIdx.x, tid = threadIdx.x;
  if (tid < NJ) {
    float s = 0.f;
    for (int ch = 0; ch < 128; ++ch) s += scorepart[(b*128 + ch)*NJ + tid];
    ss[tid] = s * (1.0f/NT);
  }
  __syncthreads();
  float m = -1e30f;
  for (int j = 0; j < NJ; ++j) m = fmaxf(m, ss[j]);
  float sum = 0.f;
  for (int j = 0; j < NJ; ++j) sum += expf(ss[j] - m);
  if (tid < NJ) {
    float a = expf(ss[tid] - m) / sum;
    attn[b*NJ + tid] = a;
    out_attn[b*NJ + tid] = a;
  }
}

// ---------------- K3: xproj^T = (h2 * attn) @ W_ih.T + bias  -- MFMA bf16
// Output layout [b][g][t]. Bias folds b_hh for r/z gates (g < 128).
__global__ __launch_bounds__(256, 2) void k3_xproj_mfma(
    const unsigned short* __restrict__ h2, const unsigned short* __restrict__ Wbf,
    const float* __restrict__ b_ih, const float* __restrict__ b_hh,
    const float* __restrict__ attn, float* __restrict__ xproj) {
  __shared__ unsigned short Abuf[2][128*32];
  __shared__ unsigned short Bbuf[2][192*32];
  const int tid = threadIdx.x;
  const int w = tid >> 6, l = tid & 63;
  const int lq = l >> 4, lr = l & 15;
  const int blk = blockIdx.x;
  const int b = blk >> 2;
  const int t0 = (blk & 3) << 7;
  const int wm = w >> 1, wn = w & 1;

  const unsigned short* gA[2]; int ldsA[2];
#pragma unroll
  for (int i = 0; i < 2; ++i) {
    const int lc = tid*2 + i, rr = lc >> 2, j = lc & 3;
    gA[i] = h2 + (size_t)(b*NT + t0 + rr)*JH + j*8;
    ldsA[i] = rr*32 + ((j ^ ((rr>>1)&3)) << 3);
  }
  const unsigned short* gB[3]; int ldsB[3];
#pragma unroll
  for (int i = 0; i < 3; ++i) {
    const int lc = tid + 256*i, g = lc >> 2, j = lc & 3;
    gB[i] = Wbf + (size_t)g*JH + j*8;
    ldsB[i] = g*32 + ((j ^ ((g>>1)&3)) << 3);
  }
  int aoff[4], boff[6];
#pragma unroll
  for (int mt = 0; mt < 4; ++mt) {
    const int row = wm*64 + mt*16 + lr;
    aoff[mt] = row*32 + ((lq ^ ((row>>1)&3)) << 3);
  }
#pragma unroll
  for (int nt = 0; nt < 6; ++nt) {
    const int g = wn*96 + nt*16 + lr;
    boff[nt] = g*32 + ((lq ^ ((g>>1)&3)) << 3);
  }

  f32x4 acc[4][6];
#pragma unroll
  for (int mt = 0; mt < 4; ++mt)
#pragma unroll
    for (int nt = 0; nt < 6; ++nt) acc[mt][nt] = (f32x4)0.f;

  {
    const float s = attn[b*NJ + 0];
#pragma unroll
    for (int i = 0; i < 2; ++i)
      *(uint4*)(&Abuf[0][ldsA[i]]) = *(const uint4*)(gA[i]);
#pragma unroll
    for (int i = 0; i < 3; ++i) {
      uint4 v = *(const uint4*)(gB[i]);
      v.x = scale2(v.x, s); v.y = scale2(v.y, s);
      v.z = scale2(v.z, s); v.w = scale2(v.w, s);
      *(uint4*)(&Bbuf[0][ldsB[i]]) = v;
    }
  }
  __syncthreads();

  for (int ks = 0; ks < 42; ++ks) {
    const int cur = ks & 1;
    uint4 av0, av1, bv0, bv1, bv2;
    if (ks < 41) {
      const int kk = (ks+1)*32;
      av0 = *(const uint4*)(gA[0] + kk);
      av1 = *(const uint4*)(gA[1] + kk);
      bv0 = *(const uint4*)(gB[0] + kk);
      bv1 = *(const uint4*)(gB[1] + kk);
      bv2 = *(const uint4*)(gB[2] + kk);
    }
    bf16x8 af[4], bfr[6];
#pragma unroll
    for (int mt = 0; mt < 4; ++mt) af[mt] = *(const bf16x8*)(&Abuf[cur][aoff[mt]]);
#pragma unroll
    for (int nt = 0; nt < 6; ++nt) bfr[nt] = *(const bf16x8*)(&Bbuf[cur][boff[nt]]);
#pragma unroll
    for (int mt = 0; mt < 4; ++mt)
#pragma unroll
      for (int nt = 0; nt < 6; ++nt)
        acc[mt][nt] = __builtin_amdgcn_mfma_f32_16x16x32_bf16(af[mt], bfr[nt], acc[mt][nt], 0, 0, 0);
    if (ks < 41) {
      const float s = attn[b*NJ + ((ks+1) >> 1)];
      *(uint4*)(&Abuf[cur^1][ldsA[0]]) = av0;
      *(uint4*)(&Abuf[cur^1][ldsA[1]]) = av1;
      uint4 v;
      v = bv0; v.x = scale2(v.x, s); v.y = scale2(v.y, s); v.z = scale2(v.z, s); v.w = scale2(v.w, s);
      *(uint4*)(&Bbuf[cur^1][ldsB[0]]) = v;
      v = bv1; v.x = scale2(v.x, s); v.y = scale2(v.y, s); v.z = scale2(v.z, s); v.w = scale2(v.w, s);
      *(uint4*)(&Bbuf[cur^1][ldsB[1]]) = v;
      v = bv2; v.x = scale2(v.x, s); v.y = scale2(v.y, s); v.z = scale2(v.z, s); v.w = scale2(v.w, s);
      *(uint4*)(&Bbuf[cur^1][ldsB[2]]) = v;
    }
    __syncthreads();
  }

  float bias[6];
#pragma unroll
  for (int nt = 0; nt < 6; ++nt) {
    const int g = wn*96 + nt*16 + lr;
    bias[nt] = b_ih[g] + (g < 2*NH ? b_hh[g] : 0.f);
  }
#pragma unroll
  for (int mt = 0; mt < 4; ++mt)
#pragma unroll
    for (int nt = 0; nt < 6; ++nt) {
      const int g = wn*96 + nt*16 + lr;
      const int trow = t0 + wm*64 + mt*16 + lq*4;
      float4 o;
      o.x = acc[mt][nt][0] + bias[nt];
      o.y = acc[mt][nt][1] + bias[nt];
      o.z = acc[mt][nt][2] + bias[nt];
      o.w = acc[mt][nt][3] + bias[nt];
      *(float4*)(&xproj[(size_t)(b*G3 + g)*NT + trow]) = o;
    }
}

// ---------------- K4: MFMA GRU v5 (R9, known-good). Lane-linear exchange,
// packed ds_write_b32, T4 raw-barrier + lgkmcnt-only drain.
__global__ __launch_bounds__(512, 1) void k4_gru_mfma(
    const float* __restrict__ xproj, const float* __restrict__ W_hh,
    const float* __restrict__ b_hh, float* __restrict__ hT) {
  __shared__ __align__(16) uint4 hb4[2][2][4][16];  // 4 KB
  const int tid = threadIdx.x;
  const int w = tid >> 6, l = tid & 63, q = l >> 4, r15 = l & 15;
  const int b0 = blockIdx.x * 16;

  for (int i = tid; i < 256; i += 512) ((uint4*)hb4)[i] = uint4{0u,0u,0u,0u};

  bf16x8 afr[2][2];
  int chv[2]; float bn_[2];
#pragma unroll
  for (int i = 0; i < 2; ++i) {
    const int mt = 2*w + i;
    const int gate = r15 & 3;
    const int cha = 8*(mt >> 1) + 2*(r15 >> 2) + (mt & 1);  // A-side channel
#pragma unroll
    for (int ks = 0; ks < 2; ++ks) {
      union { bf16x8 v; unsigned int u[4]; } tu;
      if (gate < 3) {
        const float* src = W_hh + (size_t)(gate*NH + cha)*NH + ks*32 + q*8;
        const float4 a = *(const float4*)(src);
        const float4 b = *(const float4*)(src + 4);
        tu.u[0] = pk_bf16(a.x, a.y); tu.u[1] = pk_bf16(a.z, a.w);
        tu.u[2] = pk_bf16(b.x, b.y); tu.u[3] = pk_bf16(b.z, b.w);
      } else {
        tu.u[0]=0u; tu.u[1]=0u; tu.u[2]=0u; tu.u[3]=0u;
      }
      afr[i][ks] = tu.v;
    }
    chv[i] = 8*w + 2*q + i;   // D-side channel this lane owns
    bn_[i] = b_hh[2*NH + chv[i]];
  }
  const int half = w >> 2, qblk = w & 3;

  const float* xrow[2][3];
#pragma unroll
  for (int i = 0; i < 2; ++i)
#pragma unroll
    for (int e = 0; e < 3; ++e)
      xrow[i][e] = xproj + (size_t)((b0 + r15)*G3 + e*NH + chv[i]) * NT;

  float hprev[2] = {0.f, 0.f};
  __syncthreads();   // once: hb4 zero-init visible (full drain OK here)

  f32x4 cur[2][3], nxt[2][3];
#pragma unroll
  for (int i = 0; i < 2; ++i)
#pragma unroll
    for (int e = 0; e < 3; ++e) { cur[i][e] = *(const f32x4*)(xrow[i][e]); nxt[i][e] = cur[i][e]; }

  for (int tg = 0; tg < NT; tg += 4) {
    if (tg + 4 < NT) {
#pragma unroll
      for (int i = 0; i < 2; ++i)
#pragma unroll
        for (int e = 0; e < 3; ++e) nxt[i][e] = *(const f32x4*)(xrow[i][e] + tg + 4);
    }
#pragma unroll
    for (int p = 0; p < 4; ++p) {
      const int rb = p & 1, wb = rb ^ 1;
      const bf16x8 bh0 = *(const bf16x8*)(&hb4[rb][0][q][r15]);
      const bf16x8 bh1 = *(const bf16x8*)(&hb4[rb][1][q][r15]);
      f32x4 acc[2];
      acc[0] = (f32x4)0.f; acc[1] = (f32x4)0.f;
      acc[0] = __builtin_amdgcn_mfma_f32_16x16x32_bf16(afr[0][0], bh0, acc[0], 0,0,0);
      acc[1] = __builtin_amdgcn_mfma_f32_16x16x32_bf16(afr[1][0], bh0, acc[1], 0,0,0);
      acc[0] = __builtin_amdgcn_mfma_f32_16x16x32_bf16(afr[0][1], bh1, acc[0], 0,0,0);
      acc[1] = __builtin_amdgcn_mfma_f32_16x16x32_bf16(afr[1][1], bh1, acc[1], 0,0,0);
      float hnew[2];
#pragma unroll
      for (int i = 0; i < 2; ++i) {
        const float xr = cur[i][0][p], xz = cur[i][1][p], xn = cur[i][2][p];
        const float hn = acc[i][2] + bn_[i];
        const float rr = __builtin_amdgcn_rcpf(1.f + __expf(-(xr + acc[i][0])));
        const float zz = __builtin_amdgcn_rcpf(1.f + __expf(-(xz + acc[i][1])));
        const float nx = xn + rr*hn;
        const float nn = 2.f*__builtin_amdgcn_rcpf(1.f + __expf(-2.f*nx)) - 1.f;
        hnew[i] = nn + zz*(hprev[i] - nn);
        hprev[i] = hnew[i];
      }
      ((unsigned int*)&hb4[wb][half][qblk][r15])[q] = pk_bf16(hnew[0], hnew[1]);
      // T4: LDS-only drain + raw barrier -> global prefetch stays in flight
      asm volatile("s_waitcnt lgkmcnt(0)" ::: "memory");
      __builtin_amdgcn_s_barrier();
    }
#pragma unroll
    for (int i = 0; i < 2; ++i)
#pragma unroll
      for (int e = 0; e < 3; ++e) cur[i][e] = nxt[i][e];
  }

#pragma unroll
  for (int i = 0; i < 2; ++i)
    hT[(size_t)(b0 + r15)*NH + chv[i]] = hprev[i];
}

// ---------------- K5: head
__global__ __launch_bounds__(256) void k5_head(
    const float* __restrict__ hT, const float* __restrict__ W_head,
    const float* __restrict__ b_head, float* __restrict__ out) {
  const int idx = blockIdx.x*256 + threadIdx.x;
  if (idx >= NB*63) return;
  const int b = idx / 63, rr = idx % 63;
  const float* hv = hT + b*NH;
  const float* wr = W_head + rr*NH;
  float acc = b_head[rr];
#pragma unroll
  for (int k = 0; k < NH; ++k) acc += hv[k]*wr[k];
  out[idx] = acc;
}

extern "C" void kernel_launch(void* const* d_in, const int* in_sizes, int n_in,
                              void* d_out, int out_size, void* d_ws, size_t ws_size,
                              hipStream_t stream) {
  const float* x      = (const float*)d_in[0];
  const float* A      = (const float*)d_in[1];
  const float* W1     = (const float*)d_in[2];
  const float* b1     = (const float*)d_in[3];
  const float* W2     = (const float*)d_in[4];
  const float* b2     = (const float*)d_in[5];
  const float* Wa     = (const float*)d_in[6];
  // d_in[7] = ba : softmax-invariant, unused
  const float* W_ih   = (const float*)d_in[8];
  const float* b_ih   = (const float*)d_in[9];
  const float* W_hh   = (const float*)d_in[10];
  const float* b_hh   = (const float*)d_in[11];
  const float* W_head = (const float*)d_in[12];
  const float* b_head = (const float*)d_in[13];
  float* out = (float*)d_out;

  char* ws = (char*)d_ws;
  size_t off = 0;
  unsigned short* h2 = (unsigned short*)(ws + off); off += (size_t)NB*NT*JH*2;   // 176 MB
  float* scorepart   = (float*)(ws + off);          off += (size_t)NB*128*NJ*4;  // 1.38 MB
  float* attn        = (float*)(ws + off);          off += (size_t)NB*NJ*4;
  off = (off + 15) & ~(size_t)15;
  float* xproj       = (float*)(ws + off);          off += (size_t)NB*NT*G3*4;   // 50 MB, [b][g][t]
  float* hT          = (float*)(ws + off);          off += (size_t)NB*NH*4;
  off = (off + 15) & ~(size_t)15;
  unsigned short* Wbf = (unsigned short*)(ws + off); off += (size_t)G3*JH*2;     // 516 KB

  k0_convw<<<dim3(252),       256, 0, stream>>>(W_ih, Wbf);
  k1_fused<<<dim3(NB*128),    256, 0, stream>>>(x, A, W1, b1, W2, b2, Wa, h2, scorepart);
  k2_attn<<<dim3(NB),          64, 0, stream>>>(scorepart, attn, out + OUT0);
  k3_xproj_mfma<<<dim3(512),  256, 0, stream>>>(h2, Wbf, b_ih, b_hh, attn, xproj);
  k4_gru_mfma<<<dim3(8),      512, 0, stream>>>(xproj, W_hh, b_hh, hT);
  k5_head<<<dim3((NB*63 + 255)/256), 256, 0, stream>>>(hT, W_head, b_head, out);
}